// Round 4
// baseline (192.893 us; speedup 1.0000x reference)
//
#include <hip/hip_runtime.h>
#include <hip/hip_fp16.h>

typedef __attribute__((ext_vector_type(8))) _Float16 half8;
typedef __attribute__((ext_vector_type(4))) float f32x4;

namespace {
constexpr int kMsub = 96;    // subvectors
constexpr int kK    = 256;   // codes
constexpr int kDS   = 8;     // dsub
constexpr int kD    = 768;
constexpr int kThreads = 256;   // 4 waves
constexpr int kWaves = 4;
constexpr int kBPI  = 16;       // b per wave-iter (MFMA N dim)
constexpr int kIters = 8;
constexpr int kBPB  = kWaves * kBPI * kIters;  // 512 b per block
// Candidate margin in the scaled score domain D = 256*(v.c - c2/2).
// D-gap = 128 * p-gap. Approx err (f16 3-term expansion + MFMA fp32 sum +
// denorm-flush worst case) <= ~0.017 in D units; ref-side rounding ~0.0013.
constexpr float kEPS = 0.048f;
}

// numpy pairwise sum for n=8: ((q0+q1)+(q2+q3)) + ((q4+q5)+(q6+q7))
__device__ __forceinline__ float tree8_sq(float4 a, float4 b) {
    float q0 = __fmul_rn(a.x, a.x), q1 = __fmul_rn(a.y, a.y);
    float q2 = __fmul_rn(a.z, a.z), q3 = __fmul_rn(a.w, a.w);
    float q4 = __fmul_rn(b.x, b.x), q5 = __fmul_rn(b.y, b.y);
    float q6 = __fmul_rn(b.z, b.z), q7 = __fmul_rn(b.w, b.w);
    return __fadd_rn(__fadd_rn(__fadd_rn(q0, q1), __fadd_rn(q2, q3)),
                     __fadd_rn(__fadd_rn(q4, q5), __fadd_rn(q6, q7)));
}

__device__ __forceinline__ uint pkh(__half a, __half b) {
    return (uint)__half_as_ushort(a) | ((uint)__half_as_ushort(b) << 16);
}
__device__ __forceinline__ uint pk2(float a, float b) {
    return pkh(__float2half_rn(a), __float2half_rn(b));
}
union U4H8 { uint4 u; half8 h; };
__device__ __forceinline__ half8 as_h8(uint4 u) { U4H8 x; x.u = u; return x.h; }

__global__ __launch_bounds__(kThreads)
void pq_mfma_kernel(const float* __restrict__ vecs,
                    const float* __restrict__ cbg,
                    float* __restrict__ out) {
    __shared__ uint4  s_cbh[kK];   // f16(256*c) rows
    __shared__ uint4  s_cbl[kK];   // f16 residual rows
    __shared__ uint4  s_cbq[kK];   // f16(c/8) rows
    __shared__ uint   s_c2hl[kK];  // packed f16 hi/lo of -128*c2
    __shared__ float  s_c2[kK];    // exact f32 c2 (np tree8)
    __shared__ float4 s_cb[kK][2]; // raw f32 code rows
    __shared__ float4 s_v[kWaves][kBPI][2];          // raw f32 v rows
    __shared__ __align__(16) uint2 s_vh[kWaves][kBPI][2]; // f16(v)
    __shared__ __align__(16) uint2 s_vl[kWaves][kBPI][2]; // f16(2048*(v-vh))
    __shared__ float s_v2[kWaves][kBPI];
    __shared__ int   s_win[kWaves][kBPI];

    const int tid  = threadIdx.x;
    const int lane = tid & 63;
    const int w    = tid >> 6;
    const int m    = blockIdx.x % kMsub;
    const int bt   = blockIdx.x / kMsub;
    const int g    = lane >> 4;
    const int c15  = lane & 15;

    // ---------------- staging: one code row per thread ----------------
    {
        const int k = tid;
        const float4* cr = reinterpret_cast<const float4*>(cbg + ((size_t)m * kK + k) * kDS);
        float4 c0 = cr[0], c1 = cr[1];
        s_cb[k][0] = c0; s_cb[k][1] = c1;
        float c2 = tree8_sq(c0, c1);
        s_c2[k] = c2;
        float c2s = -128.0f * c2;                 // = -256 * c2/2 (exact scale)
        __half nh = __float2half_rn(c2s);
        __half nl = __float2half_rn(c2s - __half2float(nh));
        s_c2hl[k] = pkh(nh, nl);
        float e[8] = {c0.x, c0.y, c0.z, c0.w, c1.x, c1.y, c1.z, c1.w};
        uint hh[4], ll[4], qq[4];
#pragma unroll
        for (int i = 0; i < 4; ++i) {
            float a = 256.0f * e[2*i], b = 256.0f * e[2*i+1];   // exact x256
            __half ha = __float2half_rn(a), hb = __float2half_rn(b);
            hh[i] = pkh(ha, hb);
            ll[i] = pk2(a - __half2float(ha), b - __half2float(hb)); // exact residual
            qq[i] = pk2(0.125f * e[2*i], 0.125f * e[2*i+1]);    // c/8 (exact scale)
        }
        s_cbh[k] = make_uint4(hh[0], hh[1], hh[2], hh[3]);
        s_cbl[k] = make_uint4(ll[0], ll[1], ll[2], ll[3]);
        s_cbq[k] = make_uint4(qq[0], qq[1], qq[2], qq[3]);
    }
    __syncthreads();

    // ---------------- A fragments (code side), resident ----------------
    // v_mfma_f32_16x16x32_f16: A[row=l&15][k=8*(l>>4)+j]  (row = code in tile)
    // k0-7: 256*ch ; k8-15: 256*cl ; k16-23: c/8 ; k24: -128c2_hi k25: -128c2_lo
    half8 A[16];
#pragma unroll
    for (int t = 0; t < 16; ++t) {
        const int code = t * 16 + c15;
        uint4 raw;
        if (g == 0)      raw = s_cbh[code];
        else if (g == 1) raw = s_cbl[code];
        else if (g == 2) raw = s_cbq[code];
        else             raw = make_uint4(s_c2hl[code], 0u, 0u, 0u);
        A[t] = as_h8(raw);
    }
    const f32x4 zz = {0.0f, 0.0f, 0.0f, 0.0f};

    for (int it = 0; it < kIters; ++it) {
        const size_t bg0 = (size_t)bt * kBPB + (size_t)it * (kWaves * kBPI) + (size_t)w * kBPI;

        // ---- load v rows (lanes 0-31: row c15, half g) + build f16 hi/lo
        float4 vown;
        if (lane < 32) {
            const int h = g;  // 0 or 1
            const float4* vp = reinterpret_cast<const float4*>(
                vecs + (bg0 + c15) * kD + (size_t)m * kDS) + h;
            vown = *vp;
            s_v[w][c15][h] = vown;
            __half h0 = __float2half_rn(vown.x), h1 = __float2half_rn(vown.y);
            __half h2 = __float2half_rn(vown.z), h3 = __float2half_rn(vown.w);
            uint2 vhp = { pkh(h0, h1), pkh(h2, h3) };
            uint2 vlp = { pk2(2048.0f * (vown.x - __half2float(h0)),
                              2048.0f * (vown.y - __half2float(h1))),
                          pk2(2048.0f * (vown.z - __half2float(h2)),
                              2048.0f * (vown.w - __half2float(h3))) };
            s_vh[w][c15][h] = vhp;
            s_vl[w][c15][h] = vlp;
        }
        if (lane < 16) {
            float4 vpart = s_v[w][c15][1];
            s_v2[w][c15] = tree8_sq(vown, vpart);  // np tree8, exact f32
        }

        // ---- B fragment (v side): B[k=8g+j][col=l&15]
        // g0: vh ; g1: vh ; g2: 2048*vl ; g3: [1,1,0,...]
        half8 B;
        {
            uint4 raw;
            if (g == 3) raw = make_uint4(0x3C003C00u, 0u, 0u, 0u);
            else {
                const uint4* p = (g == 2)
                    ? reinterpret_cast<const uint4*>(&s_vl[w][c15][0])
                    : reinterpret_cast<const uint4*>(&s_vh[w][c15][0]);
                raw = *p;
            }
            B = as_h8(raw);
        }
        // pairing: A(g0)=256ch * B(g0)=vh ; A(g1)=256cl * B(g1)=vh ;
        //          A(g2)=c/8   * B(g2)=2048vl ; A(g3)=c2 consts * B(g3)=1
        f32x4 D[16];
#pragma unroll
        for (int t = 0; t < 16; ++t)
            D[t] = __builtin_amdgcn_mfma_f32_16x16x32_f16(A[t], B, zz, 0, 0, 0);
        // D[row=4g+r][col=l&15] -> lane's 64 slots all belong to b=c15;
        // code = 16t + 4g + r.

        // ---- lane-local max, then 4-lane (xor 16,32) max
        float m1 = -3.402823466e38f;
#pragma unroll
        for (int t = 0; t < 16; ++t)
            m1 = fmaxf(m1, fmaxf(fmaxf(D[t].x, D[t].y), fmaxf(D[t].z, D[t].w)));
        float gmax = fmaxf(m1, __shfl_xor(m1, 16));
        gmax = fmaxf(gmax, __shfl_xor(gmax, 32));
        const float thr = gmax - kEPS;

        // ---- candidate count + (single) candidate id
        int cnt = 0, idx = 0;
#pragma unroll
        for (int t = 0; t < 16; ++t) {
            { bool ge = D[t].x >= thr; cnt += ge ? 1 : 0; idx = ge ? (t*16 + g*4 + 0) : idx; }
            { bool ge = D[t].y >= thr; cnt += ge ? 1 : 0; idx = ge ? (t*16 + g*4 + 1) : idx; }
            { bool ge = D[t].z >= thr; cnt += ge ? 1 : 0; idx = ge ? (t*16 + g*4 + 2) : idx; }
            { bool ge = D[t].w >= thr; cnt += ge ? 1 : 0; idx = ge ? (t*16 + g*4 + 3) : idx; }
        }
        int cnt4 = cnt + __shfl_xor(cnt, 16);
        cnt4 += __shfl_xor(cnt4, 32);

        if (cnt4 == 1) {
            if (cnt == 1) s_win[w][c15] = idx;   // unique winner, proven exact
        } else {
            // ---- slow path (rare): exact bitwise-numpy eval of candidates
            float4 va = s_v[w][c15][0], vb = s_v[w][c15][1];
            const float v2 = s_v2[w][c15];
            float vr[8] = {va.x, va.y, va.z, va.w, vb.x, vb.y, vb.z, vb.w};
            auto exactP = [&](int code) -> float {
                float4 ca = s_cb[code][0], cc = s_cb[code][1];
                float acc = __fmul_rn(vr[0], ca.x);
                acc = __fadd_rn(acc, __fmul_rn(vr[1], ca.y));
                acc = __fadd_rn(acc, __fmul_rn(vr[2], ca.z));
                acc = __fadd_rn(acc, __fmul_rn(vr[3], ca.w));
                acc = __fadd_rn(acc, __fmul_rn(vr[4], cc.x));
                acc = __fadd_rn(acc, __fmul_rn(vr[5], cc.y));
                acc = __fadd_rn(acc, __fmul_rn(vr[6], cc.z));
                acc = __fadd_rn(acc, __fmul_rn(vr[7], cc.w));
                return __fsub_rn(__fsub_rn(__fmul_rn(2.0f, acc), v2), s_c2[code]);
            };
            float bp = -3.402823466e38f; int bk = 1 << 30;
            if (cnt == 1) {
                bp = exactP(idx); bk = idx;
            } else if (cnt >= 2) {
#pragma unroll
                for (int t = 0; t < 16; ++t) {
                    if (D[t].x >= thr) { int c = t*16+g*4+0; float p = exactP(c); if (p > bp || (p == bp && c < bk)) { bp = p; bk = c; } }
                    if (D[t].y >= thr) { int c = t*16+g*4+1; float p = exactP(c); if (p > bp || (p == bp && c < bk)) { bp = p; bk = c; } }
                    if (D[t].z >= thr) { int c = t*16+g*4+2; float p = exactP(c); if (p > bp || (p == bp && c < bk)) { bp = p; bk = c; } }
                    if (D[t].w >= thr) { int c = t*16+g*4+3; float p = exactP(c); if (p > bp || (p == bp && c < bk)) { bp = p; bk = c; } }
                }
            }
            // lex-merge over the b's 4 lanes (all active together)
            { float p2 = __shfl_xor(bp, 16); int k2 = __shfl_xor(bk, 16);
              if (p2 > bp || (p2 == bp && k2 < bk)) { bp = p2; bk = k2; } }
            { float p2 = __shfl_xor(bp, 32); int k2 = __shfl_xor(bk, 32);
              if (p2 > bp || (p2 == bp && k2 < bk)) { bp = p2; bk = k2; } }
            if (lane < 16) s_win[w][c15] = bk;
        }

        // ---- output: copy winning code row (bitwise == reference)
        if (lane < 16) {
            const int code = s_win[w][c15];
            float4 q0 = s_cb[code][0], q1 = s_cb[code][1];
            float4* op = reinterpret_cast<float4*>(out + (bg0 + c15) * kD + (size_t)m * kDS);
            op[0] = q0;
            op[1] = q1;
        }
    }
}

extern "C" void kernel_launch(void* const* d_in, const int* in_sizes, int n_in,
                              void* d_out, int out_size, void* d_ws, size_t ws_size,
                              hipStream_t stream) {
    const float* vecs = (const float*)d_in[0];   // (8192, 768) f32
    const float* cbg  = (const float*)d_in[1];   // (96, 256, 8) f32
    float* out = (float*)d_out;                  // (8192, 768) f32

    dim3 grid(kMsub * (8192 / kBPB));            // 96 * 16 = 1536 blocks
    pq_mfma_kernel<<<grid, kThreads, 0, stream>>>(vecs, cbg, out);
}